// Round 12
// baseline (325.061 us; speedup 1.0000x reference)
//
#include <hip/hip_runtime.h>
#include <hip/hip_bf16.h>
#include <math.h>

// MSTAGNN: N nodes, E edges (propagation), FE full edges (regression head).
// HC=64, HEADS=4, HEADC=DV=16, KHOP=3, NUM_T=128.
// Design: padded CSR (64 slots/node, atomic fill); propagated state pre-scaled
// by 1/deg[src] at write time so hops are pure gather-sums; M in fp8-e4m3,
// Kf in bf16, accumulate fp32. Hop gather: 8B/lane, 2 edges/pass, 4-deep
// (32B/thread in flight — the measured-best MLP config from R7).

#define HC 64
#define HEADS 4
#define HEADC 16
#define DV 16
#define KHOP 3
#define NUM_T 128
#define MSZ 1024    // bytes per node M row (fp8)
#define SLOTS 64    // padded CSR slots per node
#define CST 1e-5f

typedef float f32x2 __attribute__((ext_vector_type(2)));

// ---- bf16 helpers (storage-only precision; accumulate in fp32) ----
__device__ __forceinline__ float bf2f(unsigned short s) { return __uint_as_float(((unsigned int)s) << 16); }
__device__ __forceinline__ unsigned short f2bf(float f) {
    unsigned int u = __float_as_uint(f);
    u = (u + 0x7fffu + ((u >> 16) & 1u)) >> 16;   // RTNE
    return (unsigned short)u;
}
// ---- fp8 e4m3 via HW pack/unpack (gfx950 OCP) ----
__device__ __forceinline__ unsigned int pack4fp8(float a, float b, float c, float d) {
    int r = __builtin_amdgcn_cvt_pk_fp8_f32(a, b, 0, false);       // bytes 0,1
    r = __builtin_amdgcn_cvt_pk_fp8_f32(c, d, r, true);            // bytes 2,3
    return (unsigned int)r;
}

// ---------------- padded-CSR fill: cnt[c]++ ; csr[c*64+k] = row ----------------
__global__ void k_fill(const int* __restrict__ row, const int* __restrict__ col,
                       int* __restrict__ cnt, int* __restrict__ csr, int E) {
    int e = blockIdx.x * 256 + threadIdx.x;
    if (e >= E) return;
    int c = col[e];
    int r = row[e];
    int k = atomicAdd(&cnt[c], 1);
    if (k < SLOTS) csr[c * SLOTS + k] = r;
}

// ------- misc: temb table (blocks 0..31) + gamma (block 0) + inv_deg (blocks 32+) -------
__global__ __launch_bounds__(256) void k_misc(
    const float* __restrict__ Wt1, const float* __restrict__ bt1,
    const float* __restrict__ Wt2, const float* __restrict__ bt2,
    const float* __restrict__ hopwise, const float* __restrict__ headwise,
    const int* __restrict__ cnt,
    float* __restrict__ gamma, float* __restrict__ table,
    float* __restrict__ inv_deg, int n) {
    if (blockIdx.x >= 32) {
        int i = (blockIdx.x - 32) * 256 + threadIdx.x;
        if (i < n) {
            int d = cnt[i];
            inv_deg[i] = (d > 0) ? 1.0f / (float)min(d, SLOTS) : 0.0f;
        }
        return;
    }
    if (blockIdx.x == 0 && threadIdx.x == 0) {
        for (int k = 0; k < KHOP; k++) {
            float m = -1e30f;
            for (int h2 = 0; h2 < HEADS; h2++) m = fmaxf(m, headwise[h2 * KHOP + k]);
            float ex[HEADS]; float s = 0.f;
            for (int h2 = 0; h2 < HEADS; h2++) { ex[h2] = expf(headwise[h2 * KHOP + k] - m); s += ex[h2]; }
            for (int h2 = 0; h2 < HEADS; h2++) gamma[k * HEADS + h2] = hopwise[k + 1] * ex[h2] / s;
        }
    }
    int slot = threadIdx.x >> 6;
    int j = threadIdx.x & 63;
    int tval = blockIdx.x * 4 + slot;                  // 0..127
    __shared__ float emb_s[4][64];
    __shared__ float z1_s[4][256];
    {
        float t = (float)tval * 31.25f;                // 4000/128
        float e;
        if (j < 32) e = sinf(t * expf(-0.2971077539347156f * (float)j));
        else        e = cosf(t * expf(-0.2971077539347156f * (float)(j - 32)));
        emb_s[slot][j] = e;
    }
    __syncthreads();
    {
        #pragma unroll
        for (int k = 0; k < 4; k++) {
            int o = j + 64 * k;
            float acc = bt1[o];
            for (int i = 0; i < 64; i++) acc += emb_s[slot][i] * Wt1[i * 256 + o];
            z1_s[slot][o] = acc / (1.f + expf(-acc));  // silu
        }
    }
    __syncthreads();
    {
        float acc = bt2[j];
        for (int i = 0; i < 256; i++) acc += z1_s[slot][i] * Wt2[i * 64 + j];
        table[tval * 64 + j] = acc;
    }
}

// ---- fused node kernel: h -> QKV -> Q, hidden, pre-scaled Kf0'(bf16), M0'(fp8)
//      16 nodes/block (1250 blocks); vectorized uint4 M0 epilogue ----
__global__ __launch_bounds__(256) void k_node(
    const float* __restrict__ x, const int* __restrict__ time_steps,
    const float* __restrict__ temb, const float* __restrict__ Wi,
    const float* __restrict__ bi,
    const float* __restrict__ WQ, const float* __restrict__ bQ,
    const float* __restrict__ WK, const float* __restrict__ bK,
    const float* __restrict__ WV, const float* __restrict__ bV,
    const float* __restrict__ hopwise, const float* __restrict__ inv_deg,
    float* __restrict__ Q, unsigned short* __restrict__ Kf0,
    unsigned char* __restrict__ M0, float* __restrict__ hidden, int n) {
    __shared__ float xs[16][128];                      // 8 KB
    __shared__ float hs[16][64];                       // 4 KB
    __shared__ unsigned short ksh[16][64];             // 2 KB  (pre-scaled Kf')
    __shared__ unsigned short vsh[16][64];             // 2 KB
    int j = threadIdx.x & 63;
    int slot = threadIdx.x >> 6;                       // wave id
    int nbase = blockIdx.x * 16;
    int nvalid = min(16, n - nbase);
    const float4* xg = (const float4*)(x + (size_t)nbase * 128);
    float4* xs4 = (float4*)&xs[0][0];
    for (int idx = threadIdx.x; idx < nvalid * 32; idx += 256) xs4[idx] = xg[idx];
    __syncthreads();
    int nl = slot * 4;
    {
        float acc[4];
        #pragma unroll
        for (int k = 0; k < 4; k++) acc[k] = 0.f;
        #pragma unroll 8
        for (int i = 0; i < 128; i++) {
            float w = Wi[i * 64 + j];
            #pragma unroll
            for (int k = 0; k < 4; k++) acc[k] += xs[nl + k][i] * w;
        }
        float bj = bi[j];
        #pragma unroll
        for (int k = 0; k < 4; k++) {
            int node = nbase + nl + k;
            float te = (node < n) ? temb[time_steps[node] * 64 + j] : 0.f;
            hs[nl + k][j] = fmaxf(acc[k] + bj + te, 0.f);
        }
    }
    __syncthreads();
    float aq[4], ak[4], av[4];
    #pragma unroll
    for (int k = 0; k < 4; k++) { aq[k] = bQ[j]; ak[k] = bK[j]; av[k] = bV[j]; }
    #pragma unroll 4
    for (int i = 0; i < 64; i++) {
        float wq = WQ[i * 64 + j], wk = WK[i * 64 + j], wv = WV[i * 64 + j];
        #pragma unroll
        for (int k = 0; k < 4; k++) {
            float hv = hs[nl + k][i];
            aq[k] += hv * wq; ak[k] += hv * wk; av[k] += hv * wv;
        }
    }
    float h0 = hopwise[0];
    #pragma unroll
    for (int k = 0; k < 4; k++) {
        int node = nbase + nl + k;
        float q  = 1.f + ((aq[k] > 0.f) ? aq[k] : (expf(aq[k]) - 1.f));
        float kf = 1.f + ((ak[k] > 0.f) ? ak[k] : (expf(ak[k]) - 1.f));
        float inv = (node < n) ? inv_deg[node] : 0.f;
        unsigned short kb = f2bf(kf * inv);            // pre-scaled Kf'
        ksh[nl + k][j] = kb;
        vsh[nl + k][j] = f2bf(av[k]);
        if (node < n) {
            Q[(size_t)node * 64 + j] = q;
            Kf0[(size_t)node * 64 + j] = kb;
            hidden[(size_t)node * 64 + j] = av[k] * h0;
        }
    }
    __syncthreads();
    // M0' epilogue: thread writes 16 consecutive fp8 (uint4).
    int t = threadIdx.x;
    #pragma unroll
    for (int it = 0; it < 4; it++) {
        int offset = it * 4096 + t * 16;
        int k = offset >> 10;
        if (k >= nvalid) break;
        int r = offset & 1023;
        int h2 = r >> 8, i2 = (r >> 4) & 15;
        float kf = bf2f(ksh[k][h2 * 16 + i2]);         // already scaled by inv_deg
        const unsigned short* vr = &vsh[k][h2 * 16];
        uint4 st;
        st.x = pack4fp8(kf * bf2f(vr[0]),  kf * bf2f(vr[1]),  kf * bf2f(vr[2]),  kf * bf2f(vr[3]));
        st.y = pack4fp8(kf * bf2f(vr[4]),  kf * bf2f(vr[5]),  kf * bf2f(vr[6]),  kf * bf2f(vr[7]));
        st.z = pack4fp8(kf * bf2f(vr[8]),  kf * bf2f(vr[9]),  kf * bf2f(vr[10]), kf * bf2f(vr[11]));
        st.w = pack4fp8(kf * bf2f(vr[12]), kf * bf2f(vr[13]), kf * bf2f(vr[14]), kf * bf2f(vr[15]));
        *(uint4*)(M0 + (size_t)nbase * MSZ + offset) = st;
    }
}

// ---- hop: block-per-node; 8B/lane × 2 edges/pass × 4-deep (32B/thread in flight) ----
__global__ __launch_bounds__(256) void k_hop(
    const unsigned char* __restrict__ Mold, const unsigned short* __restrict__ Kfold,
    const int* __restrict__ cnt, const int* __restrict__ csr,
    const float* __restrict__ inv_deg, const float* __restrict__ Q,
    const float* __restrict__ gamma,
    unsigned char* __restrict__ Mnew, unsigned short* __restrict__ Kfnew,
    float* __restrict__ hidden, int hop, int write_out,
    const float* __restrict__ Wo, const float* __restrict__ bo,
    float* __restrict__ out16) {
    int node = blockIdx.x;
    int tid = threadIdx.x;
    int half = tid >> 7;               // which edge of a pair this thread serves
    int off  = (tid & 127) * 8;        // byte range [off, off+8) of the M row
    __shared__ float smp[2][MSZ];      // 8 KB: per-half partial rows
    __shared__ float sk[64];
    __shared__ float sh[64];
    float acc[8];
    #pragma unroll
    for (int t = 0; t < 8; t++) acc[t] = 0.f;
    float kacc = 0.f;
    int deg = min(cnt[node], SLOTS);
    const int* lst = csr + (size_t)node * SLOTS;
    int d = 0;
    for (; d + 8 <= deg; d += 8) {
        int s0 = lst[d + 0 + half], s1 = lst[d + 2 + half];
        int s2 = lst[d + 4 + half], s3 = lst[d + 6 + half];
        uint2 m0 = *(const uint2*)(Mold + (size_t)s0 * MSZ + off);
        uint2 m1 = *(const uint2*)(Mold + (size_t)s1 * MSZ + off);
        uint2 m2 = *(const uint2*)(Mold + (size_t)s2 * MSZ + off);
        uint2 m3 = *(const uint2*)(Mold + (size_t)s3 * MSZ + off);
        float kr[8];
        if (tid < 64) {
            #pragma unroll
            for (int u = 0; u < 8; u++) kr[u] = bf2f(Kfold[(size_t)lst[d + u] * 64 + tid]);
        }
        const uint2 mm[4] = {m0, m1, m2, m3};
        #pragma unroll
        for (int p = 0; p < 4; p++) {
            f32x2 q;
            q = __builtin_amdgcn_cvt_pk_f32_fp8((int)mm[p].x, false); acc[0] += q.x; acc[1] += q.y;
            q = __builtin_amdgcn_cvt_pk_f32_fp8((int)mm[p].x, true);  acc[2] += q.x; acc[3] += q.y;
            q = __builtin_amdgcn_cvt_pk_f32_fp8((int)mm[p].y, false); acc[4] += q.x; acc[5] += q.y;
            q = __builtin_amdgcn_cvt_pk_f32_fp8((int)mm[p].y, true);  acc[6] += q.x; acc[7] += q.y;
        }
        if (tid < 64) {
            #pragma unroll
            for (int u = 0; u < 8; u++) kacc += kr[u];
        }
    }
    // tail: pairs (this thread handles edge d+half of each remaining pair)
    for (int e = d + half; e < deg; e += 2) {
        int s = lst[e];
        uint2 mv = *(const uint2*)(Mold + (size_t)s * MSZ + off);
        f32x2 q;
        q = __builtin_amdgcn_cvt_pk_f32_fp8((int)mv.x, false); acc[0] += q.x; acc[1] += q.y;
        q = __builtin_amdgcn_cvt_pk_f32_fp8((int)mv.x, true);  acc[2] += q.x; acc[3] += q.y;
        q = __builtin_amdgcn_cvt_pk_f32_fp8((int)mv.y, false); acc[4] += q.x; acc[5] += q.y;
        q = __builtin_amdgcn_cvt_pk_f32_fp8((int)mv.y, true);  acc[6] += q.x; acc[7] += q.y;
    }
    if (tid < 64) {
        for (int e = d; e < deg; e++) kacc += bf2f(Kfold[(size_t)lst[e] * 64 + tid]);
    }
    // stage partials
    {
        float4* dst = (float4*)&smp[half][off >> 2];   // off bytes -> off/4 floats... off is byte idx of fp8 row => float idx == byte idx
        // careful: off indexes fp8 elements (1B each); float row index == element index.
        dst = (float4*)&smp[half][off];
        dst[0] = make_float4(acc[0], acc[1], acc[2], acc[3]);
        dst[1] = make_float4(acc[4], acc[5], acc[6], acc[7]);
    }
    if (tid < 64) sk[tid] = kacc;
    __syncthreads();
    // combine halves; thread t owns final elements [t*4, t*4+4)
    {
        int idx = tid * 4;
        float t0 = smp[0][idx + 0] + smp[1][idx + 0];
        float t1 = smp[0][idx + 1] + smp[1][idx + 1];
        float t2 = smp[0][idx + 2] + smp[1][idx + 2];
        float t3 = smp[0][idx + 3] + smp[1][idx + 3];
        if (write_out) {
            float inv = inv_deg[node];
            *(unsigned int*)(Mnew + (size_t)node * MSZ + idx) =
                pack4fp8(t0 * inv, t1 * inv, t2 * inv, t3 * inv);
        }
        smp[0][idx + 0] = t0;
        smp[0][idx + 1] = t1;
        smp[0][idx + 2] = t2;
        smp[0][idx + 3] = t3;
    }
    if (write_out && tid < 64) Kfnew[(size_t)node * 64 + tid] = f2bf(sk[tid] * inv_deg[node]);
    __syncthreads();
    if (tid < 64) {
        int hh = tid >> 4, j = tid & 15;
        const float* qn = Q + (size_t)node * 64 + hh * 16;
        float C = CST, H = 0.f;
        #pragma unroll
        for (int i = 0; i < 16; i++) {
            float qv = qn[i];
            C += qv * sk[hh * 16 + i];
            H += qv * smp[0][hh * 256 + i * 16 + j];
        }
        float g = gamma[hop * HEADS + hh];
        float hid = hidden[(size_t)node * 64 + tid] + g * H / C;
        if (write_out) hidden[(size_t)node * 64 + tid] = hid;
        else sh[tid] = hid;                      // final hop: feed fused projection
    }
    if (!write_out) {
        __syncthreads();
        if (tid < 16) {
            float a = bo[tid];
            #pragma unroll 8
            for (int i = 0; i < 64; i++) a += sh[i] * Wo[i * 16 + tid];
            out16[(size_t)node * 16 + tid] = a;
        }
    }
}

// ---------------- edge regression head ----------------
__global__ __launch_bounds__(256) void k_edge(
    const int* __restrict__ src, const int* __restrict__ dst,
    const float* __restrict__ hid16,
    const float* __restrict__ Wf1, const float* __restrict__ bf1,
    const float* __restrict__ Wf2, const float* __restrict__ bf2,
    float* __restrict__ out, int fe) {
    __shared__ float w1[512];
    __shared__ float b1[16];
    __shared__ float w2[16];
    __shared__ float b2s;
    int t = threadIdx.x;
    for (int i = t; i < 512; i += 256) w1[i] = Wf1[i];
    if (t < 16) { b1[t] = bf1[t]; w2[t] = Wf2[t]; }
    if (t == 0) b2s = bf2[0];
    __syncthreads();
    int e = blockIdx.x * 256 + t;
    if (e >= fe) return;
    int s = src[e], d = dst[e];
    float he[32];
    const float4* hs4 = (const float4*)(hid16 + (size_t)s * 16);
    const float4* hd4 = (const float4*)(hid16 + (size_t)d * 16);
    #pragma unroll
    for (int q = 0; q < 4; q++) {
        float4 v = hs4[q];
        he[q * 4 + 0] = v.x; he[q * 4 + 1] = v.y; he[q * 4 + 2] = v.z; he[q * 4 + 3] = v.w;
        float4 w = hd4[q];
        he[16 + q * 4 + 0] = w.x; he[16 + q * 4 + 1] = w.y; he[16 + q * 4 + 2] = w.z; he[16 + q * 4 + 3] = w.w;
    }
    float acc = b2s;
    #pragma unroll
    for (int o = 0; o < 16; o++) {
        float z = b1[o];
        #pragma unroll
        for (int i = 0; i < 32; i++) z += he[i] * w1[i * 16 + o];
        z = z / (1.f + expf(-z));          // silu
        acc += z * w2[o];
    }
    out[e] = acc;
}

extern "C" void kernel_launch(void* const* d_in, const int* in_sizes, int n_in,
                              void* d_out, int out_size, void* d_ws, size_t ws_size,
                              hipStream_t stream) {
    const float* x        = (const float*)d_in[0];
    const int*   eidx     = (const int*)d_in[1];
    const int*   feidx    = (const int*)d_in[2];
    const int*   tsteps   = (const int*)d_in[3];
    const float* Wi  = (const float*)d_in[4];
    const float* bi  = (const float*)d_in[5];
    const float* Wt1 = (const float*)d_in[6];
    const float* bt1 = (const float*)d_in[7];
    const float* Wt2 = (const float*)d_in[8];
    const float* bt2 = (const float*)d_in[9];
    const float* WQ  = (const float*)d_in[10];
    const float* bQ  = (const float*)d_in[11];
    const float* WK  = (const float*)d_in[12];
    const float* bK  = (const float*)d_in[13];
    const float* WV  = (const float*)d_in[14];
    const float* bV  = (const float*)d_in[15];
    const float* Wo  = (const float*)d_in[16];
    const float* bo  = (const float*)d_in[17];
    const float* hopwise  = (const float*)d_in[18];
    const float* headwise = (const float*)d_in[19];
    const float* Wf1 = (const float*)d_in[20];
    const float* bf1 = (const float*)d_in[21];
    const float* Wf2 = (const float*)d_in[22];
    const float* bf2 = (const float*)d_in[23];

    const int N  = in_sizes[3];
    const int E  = in_sizes[1] / 2;
    const int FE = in_sizes[2] / 2;
    const int* row = eidx;           // [0,:]
    const int* col = eidx + E;       // [1,:]
    const int* fsrc = feidx;
    const int* fdst = feidx + FE;

    // ---- workspace carve-up (256B aligned) ----
    char* ws = (char*)d_ws;
    size_t off = 0;
    auto alloc = [&](size_t bytes) -> char* {
        char* p = ws + off;
        off = (off + bytes + 255) & ~(size_t)255;
        return p;
    };
    float* gamma     = (float*)alloc(KHOP * HEADS * sizeof(float));
    int*   cnt       = (int*)alloc((size_t)N * 4);
    int*   csr       = (int*)alloc((size_t)N * SLOTS * 4);
    float* inv_deg   = (float*)alloc((size_t)N * 4);
    float* temb      = (float*)alloc((size_t)NUM_T * HC * 4);
    float* Qbuf      = (float*)alloc((size_t)N * HC * 4);
    unsigned short* Kf0  = (unsigned short*)alloc((size_t)N * HC * 2);
    unsigned short* Kf_a = (unsigned short*)alloc((size_t)N * HC * 2);
    unsigned short* Kf_b = (unsigned short*)alloc((size_t)N * HC * 2);
    float* hidden    = (float*)alloc((size_t)N * HC * 4);
    unsigned char* M_0 = (unsigned char*)alloc((size_t)N * MSZ);
    unsigned char* M_a = (unsigned char*)alloc((size_t)N * MSZ);
    unsigned char* M_b = (unsigned char*)alloc((size_t)N * MSZ);
    (void)ws_size;

    float* out_edges = (float*)d_out;            // [FE]
    float* out_hid16 = (float*)d_out + FE;       // [N,16]

    const int miscBlocks = 32 + (N + 255) / 256;

    (void)hipMemsetAsync(cnt, 0, (size_t)N * 4, stream);
    k_fill<<<(E + 255) / 256, 256, 0, stream>>>(row, col, cnt, csr, E);
    k_misc<<<miscBlocks, 256, 0, stream>>>(Wt1, bt1, Wt2, bt2, hopwise, headwise,
                                           cnt, gamma, temb, inv_deg, N);
    k_node<<<(N + 15) / 16, 256, 0, stream>>>(x, tsteps, temb, Wi, bi,
                                              WQ, bQ, WK, bK, WV, bV, hopwise, inv_deg,
                                              Qbuf, Kf0, M_0, hidden, N);
    // hop 0: M0' -> M_a'
    k_hop<<<N, 256, 0, stream>>>(M_0, Kf0, cnt, csr, inv_deg, Qbuf, gamma,
                                 M_a, Kf_a, hidden, 0, 1, Wo, bo, out_hid16);
    // hop 1: M_a' -> M_b'
    k_hop<<<N, 256, 0, stream>>>(M_a, Kf_a, cnt, csr, inv_deg, Qbuf, gamma,
                                 M_b, Kf_b, hidden, 1, 1, Wo, bo, out_hid16);
    // hop 2: gather M_b', no write, fused output projection
    k_hop<<<N, 256, 0, stream>>>(M_b, Kf_b, cnt, csr, inv_deg, Qbuf, gamma,
                                 M_a, Kf_a, hidden, 2, 0, Wo, bo, out_hid16);
    k_edge<<<(FE + 255) / 256, 256, 0, stream>>>(fsrc, fdst, out_hid16, Wf1, bf1, Wf2, bf2,
                                                 out_edges, FE);
}

// Round 13
// 273.557 us; speedup vs baseline: 1.1883x; 1.1883x over previous
//
#include <hip/hip_runtime.h>
#include <hip/hip_bf16.h>
#include <math.h>

// MSTAGNN: N nodes, E edges (propagation), FE full edges (regression head).
// HC=64, HEADS=4, HEADC=DV=16, KHOP=3, NUM_T=128.
// Design: padded CSR (64 slots/node, atomic fill); propagated state pre-scaled
// by 1/deg[src] at write time so hops are pure gather-sums; M in fp8-e4m3,
// Kf in bf16, accumulate fp32. Hop: 2 nodes/block, 128 thr/node, 8B/lane,
// 4-deep (32B/thread in flight — R7's measured-best MLP pattern).

#define HC 64
#define HEADS 4
#define HEADC 16
#define DV 16
#define KHOP 3
#define NUM_T 128
#define MSZ 1024    // bytes per node M row (fp8)
#define SLOTS 64    // padded CSR slots per node
#define CST 1e-5f

typedef float f32x2 __attribute__((ext_vector_type(2)));

// ---- bf16 helpers (storage-only precision; accumulate in fp32) ----
__device__ __forceinline__ float bf2f(unsigned short s) { return __uint_as_float(((unsigned int)s) << 16); }
__device__ __forceinline__ unsigned short f2bf(float f) {
    unsigned int u = __float_as_uint(f);
    u = (u + 0x7fffu + ((u >> 16) & 1u)) >> 16;   // RTNE
    return (unsigned short)u;
}
// ---- fp8 e4m3 via HW pack/unpack (gfx950 OCP) ----
__device__ __forceinline__ unsigned int pack4fp8(float a, float b, float c, float d) {
    int r = __builtin_amdgcn_cvt_pk_fp8_f32(a, b, 0, false);       // bytes 0,1
    r = __builtin_amdgcn_cvt_pk_fp8_f32(c, d, r, true);            // bytes 2,3
    return (unsigned int)r;
}

// ---------------- padded-CSR fill: cnt[c]++ ; csr[c*64+k] = row ----------------
__global__ void k_fill(const int* __restrict__ row, const int* __restrict__ col,
                       int* __restrict__ cnt, int* __restrict__ csr, int E) {
    int e = blockIdx.x * 256 + threadIdx.x;
    if (e >= E) return;
    int c = col[e];
    int r = row[e];
    int k = atomicAdd(&cnt[c], 1);
    if (k < SLOTS) csr[c * SLOTS + k] = r;
}

// ------- misc: temb table (blocks 0..31) + gamma (block 0) + inv_deg (blocks 32+) -------
__global__ __launch_bounds__(256) void k_misc(
    const float* __restrict__ Wt1, const float* __restrict__ bt1,
    const float* __restrict__ Wt2, const float* __restrict__ bt2,
    const float* __restrict__ hopwise, const float* __restrict__ headwise,
    const int* __restrict__ cnt,
    float* __restrict__ gamma, float* __restrict__ table,
    float* __restrict__ inv_deg, int n) {
    if (blockIdx.x >= 32) {
        int i = (blockIdx.x - 32) * 256 + threadIdx.x;
        if (i < n) {
            int d = cnt[i];
            inv_deg[i] = (d > 0) ? 1.0f / (float)min(d, SLOTS) : 0.0f;
        }
        return;
    }
    if (blockIdx.x == 0 && threadIdx.x == 0) {
        for (int k = 0; k < KHOP; k++) {
            float m = -1e30f;
            for (int h2 = 0; h2 < HEADS; h2++) m = fmaxf(m, headwise[h2 * KHOP + k]);
            float ex[HEADS]; float s = 0.f;
            for (int h2 = 0; h2 < HEADS; h2++) { ex[h2] = expf(headwise[h2 * KHOP + k] - m); s += ex[h2]; }
            for (int h2 = 0; h2 < HEADS; h2++) gamma[k * HEADS + h2] = hopwise[k + 1] * ex[h2] / s;
        }
    }
    int slot = threadIdx.x >> 6;
    int j = threadIdx.x & 63;
    int tval = blockIdx.x * 4 + slot;                  // 0..127
    __shared__ float emb_s[4][64];
    __shared__ float z1_s[4][256];
    {
        float t = (float)tval * 31.25f;                // 4000/128
        float e;
        if (j < 32) e = sinf(t * expf(-0.2971077539347156f * (float)j));
        else        e = cosf(t * expf(-0.2971077539347156f * (float)(j - 32)));
        emb_s[slot][j] = e;
    }
    __syncthreads();
    {
        #pragma unroll
        for (int k = 0; k < 4; k++) {
            int o = j + 64 * k;
            float acc = bt1[o];
            for (int i = 0; i < 64; i++) acc += emb_s[slot][i] * Wt1[i * 256 + o];
            z1_s[slot][o] = acc / (1.f + expf(-acc));  // silu
        }
    }
    __syncthreads();
    {
        float acc = bt2[j];
        for (int i = 0; i < 256; i++) acc += z1_s[slot][i] * Wt2[i * 64 + j];
        table[tval * 64 + j] = acc;
    }
}

// ---- fused node kernel: h -> QKV -> Q, hidden, pre-scaled Kf0'(bf16), M0'(fp8)
//      16 nodes/block (1250 blocks); vectorized uint4 M0 epilogue ----
__global__ __launch_bounds__(256) void k_node(
    const float* __restrict__ x, const int* __restrict__ time_steps,
    const float* __restrict__ temb, const float* __restrict__ Wi,
    const float* __restrict__ bi,
    const float* __restrict__ WQ, const float* __restrict__ bQ,
    const float* __restrict__ WK, const float* __restrict__ bK,
    const float* __restrict__ WV, const float* __restrict__ bV,
    const float* __restrict__ hopwise, const float* __restrict__ inv_deg,
    float* __restrict__ Q, unsigned short* __restrict__ Kf0,
    unsigned char* __restrict__ M0, float* __restrict__ hidden, int n) {
    __shared__ float xs[16][128];                      // 8 KB
    __shared__ float hs[16][64];                       // 4 KB
    __shared__ unsigned short ksh[16][64];             // 2 KB  (pre-scaled Kf')
    __shared__ unsigned short vsh[16][64];             // 2 KB
    int j = threadIdx.x & 63;
    int slot = threadIdx.x >> 6;                       // wave id
    int nbase = blockIdx.x * 16;
    int nvalid = min(16, n - nbase);
    const float4* xg = (const float4*)(x + (size_t)nbase * 128);
    float4* xs4 = (float4*)&xs[0][0];
    for (int idx = threadIdx.x; idx < nvalid * 32; idx += 256) xs4[idx] = xg[idx];
    __syncthreads();
    int nl = slot * 4;
    {
        float acc[4];
        #pragma unroll
        for (int k = 0; k < 4; k++) acc[k] = 0.f;
        #pragma unroll 8
        for (int i = 0; i < 128; i++) {
            float w = Wi[i * 64 + j];
            #pragma unroll
            for (int k = 0; k < 4; k++) acc[k] += xs[nl + k][i] * w;
        }
        float bj = bi[j];
        #pragma unroll
        for (int k = 0; k < 4; k++) {
            int node = nbase + nl + k;
            float te = (node < n) ? temb[time_steps[node] * 64 + j] : 0.f;
            hs[nl + k][j] = fmaxf(acc[k] + bj + te, 0.f);
        }
    }
    __syncthreads();
    float aq[4], ak[4], av[4];
    #pragma unroll
    for (int k = 0; k < 4; k++) { aq[k] = bQ[j]; ak[k] = bK[j]; av[k] = bV[j]; }
    #pragma unroll 4
    for (int i = 0; i < 64; i++) {
        float wq = WQ[i * 64 + j], wk = WK[i * 64 + j], wv = WV[i * 64 + j];
        #pragma unroll
        for (int k = 0; k < 4; k++) {
            float hv = hs[nl + k][i];
            aq[k] += hv * wq; ak[k] += hv * wk; av[k] += hv * wv;
        }
    }
    float h0 = hopwise[0];
    #pragma unroll
    for (int k = 0; k < 4; k++) {
        int node = nbase + nl + k;
        float q  = 1.f + ((aq[k] > 0.f) ? aq[k] : (expf(aq[k]) - 1.f));
        float kf = 1.f + ((ak[k] > 0.f) ? ak[k] : (expf(ak[k]) - 1.f));
        float inv = (node < n) ? inv_deg[node] : 0.f;
        unsigned short kb = f2bf(kf * inv);            // pre-scaled Kf'
        ksh[nl + k][j] = kb;
        vsh[nl + k][j] = f2bf(av[k]);
        if (node < n) {
            Q[(size_t)node * 64 + j] = q;
            Kf0[(size_t)node * 64 + j] = kb;
            hidden[(size_t)node * 64 + j] = av[k] * h0;
        }
    }
    __syncthreads();
    // M0' epilogue: thread writes 16 consecutive fp8 (uint4).
    int t = threadIdx.x;
    #pragma unroll
    for (int it = 0; it < 4; it++) {
        int offset = it * 4096 + t * 16;
        int k = offset >> 10;
        if (k >= nvalid) break;
        int r = offset & 1023;
        int h2 = r >> 8, i2 = (r >> 4) & 15;
        float kf = bf2f(ksh[k][h2 * 16 + i2]);         // already scaled by inv_deg
        const unsigned short* vr = &vsh[k][h2 * 16];
        uint4 st;
        st.x = pack4fp8(kf * bf2f(vr[0]),  kf * bf2f(vr[1]),  kf * bf2f(vr[2]),  kf * bf2f(vr[3]));
        st.y = pack4fp8(kf * bf2f(vr[4]),  kf * bf2f(vr[5]),  kf * bf2f(vr[6]),  kf * bf2f(vr[7]));
        st.z = pack4fp8(kf * bf2f(vr[8]),  kf * bf2f(vr[9]),  kf * bf2f(vr[10]), kf * bf2f(vr[11]));
        st.w = pack4fp8(kf * bf2f(vr[12]), kf * bf2f(vr[13]), kf * bf2f(vr[14]), kf * bf2f(vr[15]));
        *(uint4*)(M0 + (size_t)nbase * MSZ + offset) = st;
    }
}

// ---- hop: 2 nodes/block, 128 thr/node; 8B/lane, 4 edges/iter (32B/thread in flight) ----
__global__ __launch_bounds__(256) void k_hop(
    const unsigned char* __restrict__ Mold, const unsigned short* __restrict__ Kfold,
    const int* __restrict__ cnt, const int* __restrict__ csr,
    const float* __restrict__ inv_deg, const float* __restrict__ Q,
    const float* __restrict__ gamma,
    unsigned char* __restrict__ Mnew, unsigned short* __restrict__ Kfnew,
    float* __restrict__ hidden, int hop, int write_out,
    const float* __restrict__ Wo, const float* __restrict__ bo,
    float* __restrict__ out16, int n) {
    int group = threadIdx.x >> 7;        // node slot within block (0/1)
    int gtid  = threadIdx.x & 127;       // thread within node group
    int node  = blockIdx.x * 2 + group;
    int off   = gtid * 8;                // this thread's 8 fp8 elements [off, off+8)
    __shared__ float sm[2][MSZ];         // 8 KB
    __shared__ float sk[2][64];
    __shared__ float sh[2][64];
    bool valid = (node < n);
    float acc[8];
    #pragma unroll
    for (int t = 0; t < 8; t++) acc[t] = 0.f;
    float kacc = 0.f;
    if (valid) {
        int deg = min(cnt[node], SLOTS);
        const int* lst = csr + (size_t)node * SLOTS;
        int d = 0;
        for (; d + 4 <= deg; d += 4) {
            int s0 = lst[d + 0], s1 = lst[d + 1], s2 = lst[d + 2], s3 = lst[d + 3];
            uint2 m0 = *(const uint2*)(Mold + (size_t)s0 * MSZ + off);
            uint2 m1 = *(const uint2*)(Mold + (size_t)s1 * MSZ + off);
            uint2 m2 = *(const uint2*)(Mold + (size_t)s2 * MSZ + off);
            uint2 m3 = *(const uint2*)(Mold + (size_t)s3 * MSZ + off);
            float kr0 = 0.f, kr1 = 0.f, kr2 = 0.f, kr3 = 0.f;
            if (gtid < 64) {
                kr0 = bf2f(Kfold[(size_t)s0 * 64 + gtid]);
                kr1 = bf2f(Kfold[(size_t)s1 * 64 + gtid]);
                kr2 = bf2f(Kfold[(size_t)s2 * 64 + gtid]);
                kr3 = bf2f(Kfold[(size_t)s3 * 64 + gtid]);
            }
            const uint2 mm[4] = {m0, m1, m2, m3};
            #pragma unroll
            for (int p = 0; p < 4; p++) {
                f32x2 q;
                q = __builtin_amdgcn_cvt_pk_f32_fp8((int)mm[p].x, false); acc[0] += q.x; acc[1] += q.y;
                q = __builtin_amdgcn_cvt_pk_f32_fp8((int)mm[p].x, true);  acc[2] += q.x; acc[3] += q.y;
                q = __builtin_amdgcn_cvt_pk_f32_fp8((int)mm[p].y, false); acc[4] += q.x; acc[5] += q.y;
                q = __builtin_amdgcn_cvt_pk_f32_fp8((int)mm[p].y, true);  acc[6] += q.x; acc[7] += q.y;
            }
            if (gtid < 64) kacc += (kr0 + kr1) + (kr2 + kr3);
        }
        for (; d < deg; d++) {
            int s = lst[d];
            uint2 mv = *(const uint2*)(Mold + (size_t)s * MSZ + off);
            f32x2 q;
            q = __builtin_amdgcn_cvt_pk_f32_fp8((int)mv.x, false); acc[0] += q.x; acc[1] += q.y;
            q = __builtin_amdgcn_cvt_pk_f32_fp8((int)mv.x, true);  acc[2] += q.x; acc[3] += q.y;
            q = __builtin_amdgcn_cvt_pk_f32_fp8((int)mv.y, false); acc[4] += q.x; acc[5] += q.y;
            q = __builtin_amdgcn_cvt_pk_f32_fp8((int)mv.y, true);  acc[6] += q.x; acc[7] += q.y;
            if (gtid < 64) kacc += bf2f(Kfold[(size_t)s * 64 + gtid]);
        }
        // stage + optional write-out
        float4* dst = (float4*)&sm[group][off];
        dst[0] = make_float4(acc[0], acc[1], acc[2], acc[3]);
        dst[1] = make_float4(acc[4], acc[5], acc[6], acc[7]);
        if (gtid < 64) sk[group][gtid] = kacc;
        if (write_out) {
            float inv = inv_deg[node];
            uint2 st;
            st.x = pack4fp8(acc[0] * inv, acc[1] * inv, acc[2] * inv, acc[3] * inv);
            st.y = pack4fp8(acc[4] * inv, acc[5] * inv, acc[6] * inv, acc[7] * inv);
            *(uint2*)(Mnew + (size_t)node * MSZ + off) = st;
            if (gtid < 64) Kfnew[(size_t)node * 64 + gtid] = f2bf(kacc * inv);
        }
    }
    __syncthreads();
    if (valid && gtid < 64) {
        int hh = gtid >> 4, j = gtid & 15;
        const float* qn = Q + (size_t)node * 64 + hh * 16;
        float C = CST, H = 0.f;
        #pragma unroll
        for (int i = 0; i < 16; i++) {
            float qv = qn[i];
            C += qv * sk[group][hh * 16 + i];
            H += qv * sm[group][hh * 256 + i * 16 + j];
        }
        float g = gamma[hop * HEADS + hh];
        float hid = hidden[(size_t)node * 64 + gtid] + g * H / C;
        if (write_out) hidden[(size_t)node * 64 + gtid] = hid;
        else sh[group][gtid] = hid;              // final hop: feed fused projection
    }
    if (!write_out) {
        __syncthreads();
        if (valid && gtid < 16) {
            float a = bo[gtid];
            #pragma unroll 8
            for (int i = 0; i < 64; i++) a += sh[group][i] * Wo[i * 16 + gtid];
            out16[(size_t)node * 16 + gtid] = a;
        }
    }
}

// ---------------- edge regression head ----------------
__global__ __launch_bounds__(256) void k_edge(
    const int* __restrict__ src, const int* __restrict__ dst,
    const float* __restrict__ hid16,
    const float* __restrict__ Wf1, const float* __restrict__ bf1,
    const float* __restrict__ Wf2, const float* __restrict__ bf2,
    float* __restrict__ out, int fe) {
    __shared__ float w1[512];
    __shared__ float b1[16];
    __shared__ float w2[16];
    __shared__ float b2s;
    int t = threadIdx.x;
    for (int i = t; i < 512; i += 256) w1[i] = Wf1[i];
    if (t < 16) { b1[t] = bf1[t]; w2[t] = Wf2[t]; }
    if (t == 0) b2s = bf2[0];
    __syncthreads();
    int e = blockIdx.x * 256 + t;
    if (e >= fe) return;
    int s = src[e], d = dst[e];
    float he[32];
    const float4* hs4 = (const float4*)(hid16 + (size_t)s * 16);
    const float4* hd4 = (const float4*)(hid16 + (size_t)d * 16);
    #pragma unroll
    for (int q = 0; q < 4; q++) {
        float4 v = hs4[q];
        he[q * 4 + 0] = v.x; he[q * 4 + 1] = v.y; he[q * 4 + 2] = v.z; he[q * 4 + 3] = v.w;
        float4 w = hd4[q];
        he[16 + q * 4 + 0] = w.x; he[16 + q * 4 + 1] = w.y; he[16 + q * 4 + 2] = w.z; he[16 + q * 4 + 3] = w.w;
    }
    float acc = b2s;
    #pragma unroll
    for (int o = 0; o < 16; o++) {
        float z = b1[o];
        #pragma unroll
        for (int i = 0; i < 32; i++) z += he[i] * w1[i * 16 + o];
        z = z / (1.f + expf(-z));          // silu
        acc += z * w2[o];
    }
    out[e] = acc;
}

extern "C" void kernel_launch(void* const* d_in, const int* in_sizes, int n_in,
                              void* d_out, int out_size, void* d_ws, size_t ws_size,
                              hipStream_t stream) {
    const float* x        = (const float*)d_in[0];
    const int*   eidx     = (const int*)d_in[1];
    const int*   feidx    = (const int*)d_in[2];
    const int*   tsteps   = (const int*)d_in[3];
    const float* Wi  = (const float*)d_in[4];
    const float* bi  = (const float*)d_in[5];
    const float* Wt1 = (const float*)d_in[6];
    const float* bt1 = (const float*)d_in[7];
    const float* Wt2 = (const float*)d_in[8];
    const float* bt2 = (const float*)d_in[9];
    const float* WQ  = (const float*)d_in[10];
    const float* bQ  = (const float*)d_in[11];
    const float* WK  = (const float*)d_in[12];
    const float* bK  = (const float*)d_in[13];
    const float* WV  = (const float*)d_in[14];
    const float* bV  = (const float*)d_in[15];
    const float* Wo  = (const float*)d_in[16];
    const float* bo  = (const float*)d_in[17];
    const float* hopwise  = (const float*)d_in[18];
    const float* headwise = (const float*)d_in[19];
    const float* Wf1 = (const float*)d_in[20];
    const float* bf1 = (const float*)d_in[21];
    const float* Wf2 = (const float*)d_in[22];
    const float* bf2 = (const float*)d_in[23];

    const int N  = in_sizes[3];
    const int E  = in_sizes[1] / 2;
    const int FE = in_sizes[2] / 2;
    const int* row = eidx;           // [0,:]
    const int* col = eidx + E;       // [1,:]
    const int* fsrc = feidx;
    const int* fdst = feidx + FE;

    // ---- workspace carve-up (256B aligned) ----
    char* ws = (char*)d_ws;
    size_t off = 0;
    auto alloc = [&](size_t bytes) -> char* {
        char* p = ws + off;
        off = (off + bytes + 255) & ~(size_t)255;
        return p;
    };
    float* gamma     = (float*)alloc(KHOP * HEADS * sizeof(float));
    int*   cnt       = (int*)alloc((size_t)N * 4);
    int*   csr       = (int*)alloc((size_t)N * SLOTS * 4);
    float* inv_deg   = (float*)alloc((size_t)N * 4);
    float* temb      = (float*)alloc((size_t)NUM_T * HC * 4);
    float* Qbuf      = (float*)alloc((size_t)N * HC * 4);
    unsigned short* Kf0  = (unsigned short*)alloc((size_t)N * HC * 2);
    unsigned short* Kf_a = (unsigned short*)alloc((size_t)N * HC * 2);
    unsigned short* Kf_b = (unsigned short*)alloc((size_t)N * HC * 2);
    float* hidden    = (float*)alloc((size_t)N * HC * 4);
    unsigned char* M_0 = (unsigned char*)alloc((size_t)N * MSZ);
    unsigned char* M_a = (unsigned char*)alloc((size_t)N * MSZ);
    unsigned char* M_b = (unsigned char*)alloc((size_t)N * MSZ);
    (void)ws_size;

    float* out_edges = (float*)d_out;            // [FE]
    float* out_hid16 = (float*)d_out + FE;       // [N,16]

    const int miscBlocks = 32 + (N + 255) / 256;
    const int hopBlocks = (N + 1) / 2;

    (void)hipMemsetAsync(cnt, 0, (size_t)N * 4, stream);
    k_fill<<<(E + 255) / 256, 256, 0, stream>>>(row, col, cnt, csr, E);
    k_misc<<<miscBlocks, 256, 0, stream>>>(Wt1, bt1, Wt2, bt2, hopwise, headwise,
                                           cnt, gamma, temb, inv_deg, N);
    k_node<<<(N + 15) / 16, 256, 0, stream>>>(x, tsteps, temb, Wi, bi,
                                              WQ, bQ, WK, bK, WV, bV, hopwise, inv_deg,
                                              Qbuf, Kf0, M_0, hidden, N);
    // hop 0: M0' -> M_a'
    k_hop<<<hopBlocks, 256, 0, stream>>>(M_0, Kf0, cnt, csr, inv_deg, Qbuf, gamma,
                                         M_a, Kf_a, hidden, 0, 1, Wo, bo, out_hid16, N);
    // hop 1: M_a' -> M_b'
    k_hop<<<hopBlocks, 256, 0, stream>>>(M_a, Kf_a, cnt, csr, inv_deg, Qbuf, gamma,
                                         M_b, Kf_b, hidden, 1, 1, Wo, bo, out_hid16, N);
    // hop 2: gather M_b', no write, fused output projection
    k_hop<<<hopBlocks, 256, 0, stream>>>(M_b, Kf_b, cnt, csr, inv_deg, Qbuf, gamma,
                                         M_a, Kf_a, hidden, 2, 0, Wo, bo, out_hid16, N);
    k_edge<<<(FE + 255) / 256, 256, 0, stream>>>(fsrc, fdst, out_hid16, Wf1, bf1, Wf2, bf2,
                                                 out_edges, FE);
}